// Round 12
// baseline (395.854 us; speedup 1.0000x reference)
//
#include <hip/hip_runtime.h>
#include <hip/hip_bf16.h>

// B=32, C=3, H=W=128, D=512, K=512, S=4, NPOS=32768
#define NPOS 32768
#define EPS_GAP 4e-3f
#define MAXSUS 4096

typedef __attribute__((ext_vector_type(8))) short short8;
typedef __attribute__((ext_vector_type(4))) float floatx4;

static __device__ __forceinline__ float bfu(unsigned short h) {
    return __uint_as_float(((unsigned int)h) << 16);
}
static __device__ __forceinline__ unsigned short f2bf(float f) {
    unsigned int u = __float_as_uint(f);
    u = (u + 0x7fffu + ((u >> 16) & 1u)) >> 16;   // RNE
    return (unsigned short)u;
}
static __device__ __forceinline__ float ldin(const void* p, size_t i, int flag) {
    return flag ? bfu(((const unsigned short*)p)[i]) : ((const float*)p)[i];
}

// ---------------------------------------------------------------------------
__global__ void k_init(int* __restrict__ scnt, int* __restrict__ nbad) {
    *scnt = 0; *nbad = 0;
}

// 64 blocks x 64 threads: block = sampled column k; shuffle-reduce sumsq.
__global__ void k_sniff(const void* __restrict__ cb, int* __restrict__ nbad) {
    const unsigned short* u = (const unsigned short*)cb;
    const int k = blockIdx.x, t = threadIdx.x;
    float acc = 0.f;
    #pragma unroll
    for (int i = 0; i < 8; ++i) {
        float v = bfu(u[(size_t)(t + 64 * i) * 512 + k]);
        acc = fmaf(v, v, acc);
    }
    #pragma unroll
    for (int m = 1; m < 64; m <<= 1) acc += __shfl_xor(acc, m);
    if (t == 0 && !(acc >= 100.f && acc <= 2000.f)) atomicAdd(nbad, 1);
}

// ---------------------------------------------------------------------------
__global__ void k_canonW(const void* __restrict__ We, const void* __restrict__ be,
                         const void* __restrict__ Wd, const void* __restrict__ bd,
                         const int* __restrict__ nbadp, float* __restrict__ cWe,
                         float* __restrict__ cbe, float* __restrict__ cWd,
                         float* __restrict__ cbd) {
    int e = blockIdx.x * 256 + threadIdx.x;
    const int flag = (*nbadp == 0);
    if (e < 24576)       cWe[e]         = ldin(We, e, flag);
    else if (e < 25088)  cbe[e - 24576] = ldin(be, e - 24576, flag);
    else if (e < 49664)  cWd[e - 25088] = ldin(Wd, e - 25088, flag);
    else if (e < 49667)  cbd[e - 49664] = ldin(bd, e - 49664, flag);
}

// ---------------------------------------------------------------------------
// cbF fp32 [d][k]; cbT fp32 [k][d]; cbHT/cbLT bf16-split [k][d].
// ---------------------------------------------------------------------------
__global__ __launch_bounds__(256) void k_prepcb(
        const void* __restrict__ cb, const int* __restrict__ nbadp,
        float* __restrict__ cbF, float* __restrict__ cbT,
        unsigned short* __restrict__ cbHT, unsigned short* __restrict__ cbLT) {
    __shared__ float tile[64][65];
    const int flag = (*nbadp == 0);
    const int D0 = blockIdx.x * 64, K0 = blockIdx.y * 64;
    const int t = threadIdx.x;
    for (int it = 0; it < 16; ++it) {
        int r = (t >> 6) + 4 * it, c = t & 63;
        float v = ldin(cb, (size_t)(D0 + r) * 512 + K0 + c, flag);
        cbF[(size_t)(D0 + r) * 512 + K0 + c] = v;
        tile[r][c] = v;
    }
    __syncthreads();
    for (int it = 0; it < 16; ++it) {
        int r = (t >> 6) + 4 * it, c = t & 63;
        float v = tile[c][r];
        size_t o = (size_t)(K0 + r) * 512 + D0 + c;
        cbT[o] = v;
        unsigned short h = f2bf(v);
        cbHT[o] = h;
        cbLT[o] = f2bf(v - bfu(h));
    }
}

// ---------------------------------------------------------------------------
// w2 from cbT rows (contiguous, coalesced): 512 blocks x 64 threads.
// ---------------------------------------------------------------------------
__global__ void k_w2(const float* __restrict__ cbT, float* __restrict__ w2,
                     double* __restrict__ w2d) {
    const int k = blockIdx.x, t = threadIdx.x;
    double acc = 0.0;
    #pragma unroll
    for (int i = 0; i < 8; ++i) {
        double v = (double)cbT[(size_t)k * 512 + t + 64 * i];
        acc += v * v;
    }
    #pragma unroll
    for (int m = 1; m < 64; m <<= 1) acc += __shfl_xor(acc, m);
    if (t == 0) { w2[k] = (float)acc; w2d[k] = acc; }
}

// ---------------------------------------------------------------------------
// U[k][c*16+u*4+v] = sum_d cbF[d][k]*cWd[c][d][3-u][3-v] + cbd[c]
// ---------------------------------------------------------------------------
__global__ __launch_bounds__(256) void k_udec(
        const float* __restrict__ cbF, const float* __restrict__ cWd,
        const float* __restrict__ cbd, float* __restrict__ U) {
    const int t = threadIdx.x;
    const int k = blockIdx.x * 4 + (t >> 6);
    const int lane = t & 63;
    const int j = lane >> 2, dpart = lane & 3;
    const int u = (j >> 2) & 3, v = j & 3;
    int woff[3];
    #pragma unroll
    for (int m = 0; m < 3; ++m) woff[m] = m * 8192 + (3 - u) * 4 + (3 - v);
    float a0 = 0.f, a1 = 0.f, a2 = 0.f;
    for (int i = 0; i < 128; ++i) {
        int d = dpart * 128 + i;
        float cw = cbF[(size_t)d * 512 + k];
        a0 = fmaf(cw, cWd[woff[0] + d * 16], a0);
        a1 = fmaf(cw, cWd[woff[1] + d * 16], a1);
        a2 = fmaf(cw, cWd[woff[2] + d * 16], a2);
    }
    a0 += __shfl_xor(a0, 1); a0 += __shfl_xor(a0, 2);
    a1 += __shfl_xor(a1, 1); a1 += __shfl_xor(a1, 2);
    a2 += __shfl_xor(a2, 1); a2 += __shfl_xor(a2, 2);
    if (dpart == 0) {
        U[k * 48 +  0 + j] = a0 + cbd[0];
        U[k * 48 + 16 + j] = a1 + cbd[1];
        U[k * 48 + 32 + j] = a2 + cbd[2];
    }
}

// ---------------------------------------------------------------------------
// k_main v4 helpers. 32 pos/block. z pair buffer = 2560 shorts:
//   H at [pos*40 + d], L at [1280 + pos*40 + d].
// ---------------------------------------------------------------------------
static __device__ __forceinline__ void conv_step(
        const float* __restrict__ patch, const float* __restrict__ cWe,
        const float* __restrict__ cbe, int dc, int t, int b, int SP0,
        unsigned short* __restrict__ zq, float* __restrict__ out_z) {
    const int cd = t & 31;
    const int ps = (t >> 5) * 4;
    const float4* wv = (const float4*)(cWe + (size_t)(dc + cd) * 48);
    const float bias = cbe[dc + cd];
    float za[4];
    #pragma unroll
    for (int p = 0; p < 4; ++p) za[p] = bias;
    #pragma unroll
    for (int q4 = 0; q4 < 12; ++q4) {
        float4 wq = wv[q4];
        #pragma unroll
        for (int p = 0; p < 4; ++p) {
            float4 v = ((const float4*)(patch + (ps + p) * 48))[q4];
            za[p] = fmaf(v.x, wq.x, za[p]);
            za[p] = fmaf(v.y, wq.y, za[p]);
            za[p] = fmaf(v.z, wq.z, za[p]);
            za[p] = fmaf(v.w, wq.w, za[p]);
        }
    }
    float4 zo;
    float* zf = (float*)&zo;
    #pragma unroll
    for (int p = 0; p < 4; ++p) {
        float z = fmaxf(za[p], 0.f);
        zf[p] = z;
        unsigned short h = f2bf(z);
        zq[(ps + p) * 40 + cd] = h;
        zq[1280 + (ps + p) * 40 + cd] = f2bf(z - bfu(h));
    }
    *(float4*)(&out_z[(size_t)(b * 512 + dc + cd) * 1024 + SP0 + ps]) = zo;
}

static __device__ __forceinline__ void mfma_step(
        const unsigned short* __restrict__ zq,
        const unsigned short* __restrict__ cbHT,
        const unsigned short* __restrict__ cbLT,
        int dcPrev, int wave, int quad, int lcol, int flag, floatx4 (&acc)[2][8]) {
    short8 aH[2], aL[2];
    #pragma unroll
    for (int mt = 0; mt < 2; ++mt) {
        aH[mt] = *(const short8*)(zq + (mt * 16 + lcol) * 40 + quad * 8);
        aL[mt] = *(const short8*)(zq + 1280 + (mt * 16 + lcol) * 40 + quad * 8);
    }
    #pragma unroll
    for (int j = 0; j < 8; ++j) {
        int code = (wave * 8 + j) * 16 + lcol;
        short8 bH = *(const short8*)(cbHT + (size_t)code * 512 + dcPrev + quad * 8);
        #pragma unroll
        for (int mt = 0; mt < 2; ++mt) {
            acc[mt][j] = __builtin_amdgcn_mfma_f32_16x16x32_bf16(aH[mt], bH, acc[mt][j], 0, 0, 0);
            acc[mt][j] = __builtin_amdgcn_mfma_f32_16x16x32_bf16(aL[mt], bH, acc[mt][j], 0, 0, 0);
        }
    }
    if (!flag) {   // fp32 inputs: third term zh*cbL
        #pragma unroll
        for (int j = 0; j < 8; ++j) {
            int code = (wave * 8 + j) * 16 + lcol;
            short8 bL = *(const short8*)(cbLT + (size_t)code * 512 + dcPrev + quad * 8);
            #pragma unroll
            for (int mt = 0; mt < 2; ++mt)
                acc[mt][j] = __builtin_amdgcn_mfma_f32_16x16x32_bf16(aH[mt], bL, acc[mt][j], 0, 0, 0);
        }
    }
}

static __device__ __forceinline__ void bmerge(float& a1, int& ak, float& a2,
                                              float o1, int ok, float o2) {
    if (o1 < a1)      { a2 = fminf(a1, o2); a1 = o1; ak = ok; }
    else if (o1 > a1) { a2 = fminf(a2, o1); }
    else              { a2 = a1; if (ok < ak) ak = ok; }   // exact tie -> gap 0 (suspect)
}

// ---------------------------------------------------------------------------
// FUSED main v4: 1024 blocks x 32 pos (4 blocks/CU), single barrier per chunk.
//   iter dc: sync; conv(dc)->buf p (+direct out_z store); mfma(dc-32)<-buf 1-p.
// LDS: patch 6144 B | z pairs 2x5120 B = 16384 B.
// ---------------------------------------------------------------------------
__global__ __launch_bounds__(256, 4) void k_main(
        const void* __restrict__ x, const float* __restrict__ cWe,
        const float* __restrict__ cbe, const int* __restrict__ nbadp,
        const unsigned short* __restrict__ cbHT, const unsigned short* __restrict__ cbLT,
        const float* __restrict__ cbT, const float* __restrict__ w2,
        float* __restrict__ out_z, float* __restrict__ out_e,
        int* __restrict__ idx, int* __restrict__ scnt, int* __restrict__ spos,
        int skipTail) {
    __shared__ __align__(16) char smc[16384];
    float* patch = (float*)smc;                               // [32][48] fp32
    unsigned short* zb = (unsigned short*)(smc + 6144);       // 2 pairs x 2560 shorts

    const int t = threadIdx.x;
    const int P0 = blockIdx.x * 32;
    const int b = P0 >> 10, SP0 = P0 & 1023;
    const int flag = (*nbadp == 0);
    const int wave = t >> 6, lane = t & 63;
    const int quad = lane >> 4, lcol = lane & 15;

    // stage x patches once: 32 pos x 48 taps
    for (int e = t; e < 1536; e += 256) {
        int pid = e / 48, kk = e % 48;
        int c = kk >> 4, r = (kk >> 2) & 3, s = kk & 3;
        int pos = P0 + pid;
        int bb = pos >> 10, sp = pos & 1023, i = sp >> 5, j = sp & 31;
        patch[pid * 48 + kk] = ldin(x, ((bb * 3 + c) * 128 + (i * 4 + r)) * 128 + (j * 4 + s), flag);
    }

    floatx4 acc[2][8];
    #pragma unroll
    for (int mt = 0; mt < 2; ++mt)
        #pragma unroll
        for (int j = 0; j < 8; ++j) acc[mt][j] = (floatx4){0.f, 0.f, 0.f, 0.f};

    __syncthreads();
    conv_step(patch, cWe, cbe, 0, t, b, SP0, zb, out_z);       // chunk 0 -> pair 0
    for (int dc = 32; dc < 512; dc += 32) {
        __syncthreads();
        const int p = (dc >> 5) & 1;
        conv_step(patch, cWe, cbe, dc, t, b, SP0, zb + p * 2560, out_z);
        mfma_step(zb + (p ^ 1) * 2560, cbHT, cbLT, dc - 32, wave, quad, lcol, flag, acc);
    }
    __syncthreads();
    mfma_step(zb + 2560, cbHT, cbLT, 480, wave, quad, lcol, flag, acc);

    // ---- epilogue: per-lane best/second, shuffle-reduce over 16 lanes ----
    float s1[2][4], s2[2][4]; int k1[2][4];
    #pragma unroll
    for (int mt = 0; mt < 2; ++mt)
        #pragma unroll
        for (int r = 0; r < 4; ++r) { s1[mt][r] = 1e30f; s2[mt][r] = 1e30f; k1[mt][r] = 511; }
    #pragma unroll
    for (int j = 0; j < 8; ++j) {
        int code = (wave * 8 + j) * 16 + lcol;
        float wk = w2[code];
        #pragma unroll
        for (int mt = 0; mt < 2; ++mt)
            #pragma unroll
            for (int r = 0; r < 4; ++r) {
                float s = wk - 2.f * acc[mt][j][r];
                bmerge(s1[mt][r], k1[mt][r], s2[mt][r], s, code, 1e30f);
            }
    }
    // overlay reduction arrays on patch region (dead after last conv + barrier)
    float* sS1 = (float*)smc;             // [32 pos][4 wave]
    int*   sK1 = (int*)(smc + 512);
    float* sS2 = (float*)(smc + 1024);
    int*   ii  = (int*)(smc + 1536);      // [32]
    #pragma unroll
    for (int mt = 0; mt < 2; ++mt)
        #pragma unroll
        for (int r = 0; r < 4; ++r) {
            float a1 = s1[mt][r], a2 = s2[mt][r]; int ak = k1[mt][r];
            #pragma unroll
            for (int m = 1; m < 16; m <<= 1) {
                float o1 = __shfl_xor(a1, m);
                float o2 = __shfl_xor(a2, m);
                int   ok = __shfl_xor(ak, m);
                bmerge(a1, ak, a2, o1, ok, o2);
            }
            if (lcol == 0) {
                int pos = mt * 16 + quad * 4 + r;
                sS1[pos * 4 + wave] = a1;
                sK1[pos * 4 + wave] = ak;
                sS2[pos * 4 + wave] = a2;
            }
        }
    __syncthreads();
    if (t < 32) {
        float a1 = sS1[t * 4]; int ak = sK1[t * 4]; float a2 = sS2[t * 4];
        #pragma unroll
        for (int w = 1; w < 4; ++w)
            bmerge(a1, ak, a2, sS1[t * 4 + w], sK1[t * 4 + w], sS2[t * 4 + w]);
        ak &= 511;
        ii[t] = ak;
        idx[P0 + t] = ak;
        if (a2 - a1 < EPS_GAP) {
            int slot = atomicAdd(scnt, 1);
            if (slot < MAXSUS) spos[slot] = P0 + t;
        }
    }
    __syncthreads();

    // ---- fused emb: out_e[b][d][SP0+sp] = cbT[ii[sp]][d] ----
    const int sp = t & 31, dq = t >> 5;   // 8 strips of 64 d
    const float* row = cbT + (size_t)ii[sp] * 512;
    const size_t obase = ((size_t)b * 512) * 1024 + SP0 + sp;
    for (int d0 = dq * 64; d0 < dq * 64 + 64; d0 += 4) {
        if (skipTail && b == 31 && d0 >= 448) break;
        float4 v = *(const float4*)(row + d0);
        out_e[obase + (size_t)(d0    ) * 1024] = v.x;
        out_e[obase + (size_t)(d0 + 1) * 1024] = v.y;
        out_e[obase + (size_t)(d0 + 2) * 1024] = v.z;
        out_e[obase + (size_t)(d0 + 3) * 1024] = v.w;
    }
}

// ---------------------------------------------------------------------------
// Exact fp64 rescore of suspect positions; patches idx and emb column.
// ---------------------------------------------------------------------------
__global__ __launch_bounds__(256) void k_rescore(
        const float* __restrict__ out_z, const float* __restrict__ cbT,
        const double* __restrict__ w2d, int* __restrict__ idx,
        const int* __restrict__ scnt, const int* __restrict__ spos,
        float* __restrict__ out_e, int skipTail) {
    __shared__ float zsh[512];
    __shared__ float rs[256];
    __shared__ int rk[256];
    __shared__ int bc[2];
    const int t = threadIdx.x;
    int n = *scnt; if (n > MAXSUS) n = MAXSUS;
    for (int s = blockIdx.x; s < n; s += gridDim.x) {
        int p = spos[s] & 32767;
        int b = p >> 10, sp = p & 1023;
        __syncthreads();
        zsh[t]       = out_z[(size_t)(b * 512 + t) * 1024 + sp];
        zsh[t + 256] = out_z[(size_t)(b * 512 + t + 256) * 1024 + sp];
        __syncthreads();
        float bs = 1e30f; int bk = 511;
        for (int cc = 0; cc < 2; ++cc) {
            int k = t + cc * 256;
            double a = 0.0;
            const float* row = cbT + (size_t)k * 512;
            for (int d = 0; d < 512; ++d) a = fma((double)zsh[d], (double)row[d], a);
            float sc = (float)(w2d[k] - 2.0 * a);
            if (sc < bs || (sc == bs && k < bk)) { bs = sc; bk = k; }
        }
        rs[t] = bs; rk[t] = bk;
        __syncthreads();
        for (int str = 128; str > 0; str >>= 1) {
            if (t < str) {
                float so = rs[t + str]; int ko = rk[t + str];
                if (so < rs[t] || (so == rs[t] && ko < rk[t])) { rs[t] = so; rk[t] = ko; }
            }
            __syncthreads();
        }
        if (t == 0) {
            int kstar = rk[0] & 511;
            int old = idx[p] & 511;
            bc[0] = kstar; bc[1] = (kstar != old);
            idx[p] = kstar;
        }
        __syncthreads();
        if (bc[1]) {
            int kk = bc[0];
            for (int d = t; d < 512; d += 256) {
                if (skipTail && b == 31 && d >= 448) continue;
                out_e[(size_t)(b * 512 + d) * 1024 + sp] = cbT[(size_t)kk * 512 + d];
            }
        }
    }
}

// ---------------------------------------------------------------------------
__global__ __launch_bounds__(256) void k_recon(
        const float* __restrict__ U, const int* __restrict__ idx,
        float* __restrict__ out_r) {
    const int pos = blockIdx.x * 256 + threadIdx.x;
    const int id = idx[pos] & 511;
    const int b = pos >> 10, sp = pos & 1023, i = sp >> 5, j = sp & 31;
    const float* u = &U[(size_t)id * 48];
    #pragma unroll
    for (int c = 0; c < 3; ++c)
        #pragma unroll
        for (int uu = 0; uu < 4; ++uu) {
            float4 q = *(const float4*)(&u[c * 16 + uu * 4]);
            float4 o;
            o.x = 1.f / (1.f + __expf(-q.x));
            o.y = 1.f / (1.f + __expf(-q.y));
            o.z = 1.f / (1.f + __expf(-q.z));
            o.w = 1.f / (1.f + __expf(-q.w));
            *(float4*)(&out_r[((size_t)((b * 3 + c) * 128) + (i * 4 + uu)) * 128 + j * 4]) = o;
        }
}

// ---------------------------------------------------------------------------
__global__ __launch_bounds__(1024) void k_fixup(
        const void* __restrict__ cb, const int* __restrict__ nbadp,
        const int* __restrict__ idx, float* __restrict__ out_e) {
    __shared__ int ii[1024];
    __shared__ int sflag;
    const int t = threadIdx.x;
    if (t == 0) sflag = (*nbadp == 0);
    ii[t] = idx[31744 + t] & 511;
    __syncthreads();
    const int flag = sflag;
    for (int e = t; e < 65536; e += 1024) {
        int d = 448 + (e >> 10), sp = e & 1023;
        out_e[((size_t)(31 * 512 + d)) * 1024 + sp] = ldin(cb, (size_t)d * 512 + ii[sp], flag);
    }
}

// ---------------------------------------------------------------------------
extern "C" void kernel_launch(void* const* d_in, const int* in_sizes, int n_in,
                              void* d_out, int out_size, void* d_ws, size_t ws_size,
                              hipStream_t stream) {
    const void* x  = d_in[0];
    const void* We = d_in[1];
    const void* be = d_in[2];
    const void* Wd = d_in[3];
    const void* bd = d_in[4];
    const void* cb = d_in[5];

    float* out   = (float*)d_out;
    float* out_r = out;                       // 1,572,864 fp32 (6.29 MB)
    float* out_z = out + 1572864;             // 16,777,216 fp32
    float* out_e = out + 18350080;            // 16,777,216 fp32

    // Read-mostly tables in out_r (recon overwrites at the very end):
    char* Rb = (char*)out_r;
    float* cbF          = (float*)(Rb);                    // 1,048,576 B
    float* cbT          = (float*)(Rb + 1048576);          // 1,048,576 B
    float* cWe          = (float*)(Rb + 2097152);          //    98,304 B
    float* cbe          = (float*)(Rb + 2195456);          //     2,048 B
    float* cWd          = (float*)(Rb + 2197504);          //    98,304 B
    float* cbd          = (float*)(Rb + 2295808);          //        64 B
    unsigned short* cbHT= (unsigned short*)(Rb + 2295872); //   524,288 B
    unsigned short* cbLT= (unsigned short*)(Rb + 2820160); //   524,288 B

    // Tail scratch: prefer d_ws; else last 256 KB of out_e (fixup required).
    int tailWS = (ws_size >= 262144) ? 1 : 0;
    char* Tbase = tailWS ? (char*)d_ws : ((char*)out_e + 66846720);
    int skipTail = tailWS ? 0 : 1;
    int*    idx  = (int*)   (Tbase);            // 131,072 B
    float*  U    = (float*) (Tbase + 131072);   //  98,304 B
    float*  w2   = (float*) (Tbase + 229376);   //   2,048 B
    double* w2d  = (double*)(Tbase + 231424);   //   4,096 B
    int*    nbad = (int*)   (Tbase + 235520);   //      64 B
    int*    scnt = (int*)   (Tbase + 235584);   //      64 B
    int*    spos = (int*)   (Tbase + 235648);   //  16,384 B

    k_init<<<1, 1, 0, stream>>>(scnt, nbad);
    k_sniff<<<64, 64, 0, stream>>>(cb, nbad);
    k_canonW<<<195, 256, 0, stream>>>(We, be, Wd, bd, nbad, cWe, cbe, cWd, cbd);
    k_prepcb<<<dim3(8, 8), 256, 0, stream>>>(cb, nbad, cbF, cbT, cbHT, cbLT);
    k_w2<<<512, 64, 0, stream>>>(cbT, w2, w2d);
    k_udec<<<128, 256, 0, stream>>>(cbF, cWd, cbd, U);

    k_main<<<1024, 256, 0, stream>>>(x, cWe, cbe, nbad, cbHT, cbLT, cbT, w2,
                                     out_z, out_e, idx, scnt, spos, skipTail);

    k_rescore<<<128, 256, 0, stream>>>(out_z, cbT, w2d, idx, scnt, spos, out_e, skipTail);
    k_recon<<<128, 256, 0, stream>>>(U, idx, out_r);
    if (skipTail)
        k_fixup<<<1, 1024, 0, stream>>>(cb, nbad, idx, out_e);
}

// Round 13
// 378.662 us; speedup vs baseline: 1.0454x; 1.0454x over previous
//
#include <hip/hip_runtime.h>
#include <hip/hip_bf16.h>

// B=32, C=3, H=W=128, D=512, K=512, S=4, NPOS=32768
#define NPOS 32768
#define EPS_GAP 4e-3f
#define MAXSUS 4096

typedef __attribute__((ext_vector_type(8))) short short8;
typedef __attribute__((ext_vector_type(4))) float floatx4;

static __device__ __forceinline__ float bfu(unsigned short h) {
    return __uint_as_float(((unsigned int)h) << 16);
}
static __device__ __forceinline__ unsigned short f2bf(float f) {
    unsigned int u = __float_as_uint(f);
    u = (u + 0x7fffu + ((u >> 16) & 1u)) >> 16;   // RNE
    return (unsigned short)u;
}
static __device__ __forceinline__ float ldin(const void* p, size_t i, int flag) {
    return flag ? bfu(((const unsigned short*)p)[i]) : ((const float*)p)[i];
}

// ---------------------------------------------------------------------------
__global__ void k_init(int* __restrict__ scnt, int* __restrict__ nbad) {
    *scnt = 0; *nbad = 0;
}

// 64 blocks x 64 threads: block = column k; shuffle-reduce sumsq.
__global__ void k_sniff(const void* __restrict__ cb, int* __restrict__ nbad) {
    const unsigned short* u = (const unsigned short*)cb;
    const int k = blockIdx.x, t = threadIdx.x;
    float acc = 0.f;
    #pragma unroll
    for (int i = 0; i < 8; ++i) {
        float v = bfu(u[(size_t)(t + 64 * i) * 512 + k]);
        acc = fmaf(v, v, acc);
    }
    #pragma unroll
    for (int m = 1; m < 64; m <<= 1) acc += __shfl_xor(acc, m);
    if (t == 0 && !(acc >= 100.f && acc <= 2000.f)) atomicAdd(nbad, 1);
}

// ---------------------------------------------------------------------------
__global__ void k_canonW(const void* __restrict__ We, const void* __restrict__ be,
                         const void* __restrict__ Wd, const void* __restrict__ bd,
                         const int* __restrict__ nbadp, float* __restrict__ cWe,
                         float* __restrict__ cbe, float* __restrict__ cWd,
                         float* __restrict__ cbd) {
    int e = blockIdx.x * 256 + threadIdx.x;
    const int flag = (*nbadp == 0);
    if (e < 24576)       cWe[e]         = ldin(We, e, flag);
    else if (e < 25088)  cbe[e - 24576] = ldin(be, e - 24576, flag);
    else if (e < 49664)  cWd[e - 25088] = ldin(Wd, e - 25088, flag);
    else if (e < 49667)  cbd[e - 49664] = ldin(bd, e - 49664, flag);
}

// ---------------------------------------------------------------------------
// cbF fp32 [d][k]; cbT fp32 [k][d]; cbHT/cbLT bf16-split [k][d].
// ---------------------------------------------------------------------------
__global__ __launch_bounds__(256) void k_prepcb(
        const void* __restrict__ cb, const int* __restrict__ nbadp,
        float* __restrict__ cbF, float* __restrict__ cbT,
        unsigned short* __restrict__ cbHT, unsigned short* __restrict__ cbLT) {
    __shared__ float tile[64][65];
    const int flag = (*nbadp == 0);
    const int D0 = blockIdx.x * 64, K0 = blockIdx.y * 64;
    const int t = threadIdx.x;
    for (int it = 0; it < 16; ++it) {
        int r = (t >> 6) + 4 * it, c = t & 63;
        float v = ldin(cb, (size_t)(D0 + r) * 512 + K0 + c, flag);
        cbF[(size_t)(D0 + r) * 512 + K0 + c] = v;
        tile[r][c] = v;
    }
    __syncthreads();
    for (int it = 0; it < 16; ++it) {
        int r = (t >> 6) + 4 * it, c = t & 63;
        float v = tile[c][r];
        size_t o = (size_t)(K0 + r) * 512 + D0 + c;
        cbT[o] = v;
        unsigned short h = f2bf(v);
        cbHT[o] = h;
        cbLT[o] = f2bf(v - bfu(h));
    }
}

// ---------------------------------------------------------------------------
__global__ void k_w2(const float* __restrict__ cbT, float* __restrict__ w2,
                     double* __restrict__ w2d) {
    const int k = blockIdx.x, t = threadIdx.x;
    double acc = 0.0;
    #pragma unroll
    for (int i = 0; i < 8; ++i) {
        double v = (double)cbT[(size_t)k * 512 + t + 64 * i];
        acc += v * v;
    }
    #pragma unroll
    for (int m = 1; m < 64; m <<= 1) acc += __shfl_xor(acc, m);
    if (t == 0) { w2[k] = (float)acc; w2d[k] = acc; }
}

// ---------------------------------------------------------------------------
// U[k][c*16+u*4+v] = sum_d cbF[d][k]*cWd[c][d][3-u][3-v] + cbd[c]
// ---------------------------------------------------------------------------
__global__ __launch_bounds__(256) void k_udec(
        const float* __restrict__ cbF, const float* __restrict__ cWd,
        const float* __restrict__ cbd, float* __restrict__ U) {
    const int t = threadIdx.x;
    const int k = blockIdx.x * 4 + (t >> 6);
    const int lane = t & 63;
    const int j = lane >> 2, dpart = lane & 3;
    const int u = (j >> 2) & 3, v = j & 3;
    int woff[3];
    #pragma unroll
    for (int m = 0; m < 3; ++m) woff[m] = m * 8192 + (3 - u) * 4 + (3 - v);
    float a0 = 0.f, a1 = 0.f, a2 = 0.f;
    for (int i = 0; i < 128; ++i) {
        int d = dpart * 128 + i;
        float cw = cbF[(size_t)d * 512 + k];
        a0 = fmaf(cw, cWd[woff[0] + d * 16], a0);
        a1 = fmaf(cw, cWd[woff[1] + d * 16], a1);
        a2 = fmaf(cw, cWd[woff[2] + d * 16], a2);
    }
    a0 += __shfl_xor(a0, 1); a0 += __shfl_xor(a0, 2);
    a1 += __shfl_xor(a1, 1); a1 += __shfl_xor(a1, 2);
    a2 += __shfl_xor(a2, 1); a2 += __shfl_xor(a2, 2);
    if (dpart == 0) {
        U[k * 48 +  0 + j] = a0 + cbd[0];
        U[k * 48 + 16 + j] = a1 + cbd[1];
        U[k * 48 + 32 + j] = a2 + cbd[2];
    }
}

// ---------------------------------------------------------------------------
// k_main v5 helpers. 32 pos/block. z pair buffer = 2560 shorts:
//   H at [pos*40 + d], L at [1280 + pos*40 + d].
// ---------------------------------------------------------------------------
static __device__ __forceinline__ void conv_step(
        const float* __restrict__ patch, const float* __restrict__ cWe,
        const float* __restrict__ cbe, int dc, int t,
        unsigned short* __restrict__ zq) {
    const int cd = t & 31;
    const int ps = (t >> 5) * 4;
    const float4* wv = (const float4*)(cWe + (size_t)(dc + cd) * 48);
    const float bias = cbe[dc + cd];
    float za[4];
    #pragma unroll
    for (int p = 0; p < 4; ++p) za[p] = bias;
    #pragma unroll
    for (int q4 = 0; q4 < 12; ++q4) {
        float4 wq = wv[q4];
        #pragma unroll
        for (int p = 0; p < 4; ++p) {
            float4 v = ((const float4*)(patch + (ps + p) * 48))[q4];
            za[p] = fmaf(v.x, wq.x, za[p]);
            za[p] = fmaf(v.y, wq.y, za[p]);
            za[p] = fmaf(v.z, wq.z, za[p]);
            za[p] = fmaf(v.w, wq.w, za[p]);
        }
    }
    #pragma unroll
    for (int p = 0; p < 4; ++p) {
        float z = fmaxf(za[p], 0.f);
        unsigned short h = f2bf(z);
        zq[(ps + p) * 40 + cd] = h;
        zq[1280 + (ps + p) * 40 + cd] = f2bf(z - bfu(h));
    }
}

static __device__ __forceinline__ void mfma_step(
        const unsigned short* __restrict__ zq,
        const unsigned short* __restrict__ cbHT,
        const unsigned short* __restrict__ cbLT,
        int dcPrev, int wave, int quad, int lcol, int flag, floatx4 (&acc)[2][8]) {
    short8 aH[2], aL[2];
    #pragma unroll
    for (int mt = 0; mt < 2; ++mt) {
        aH[mt] = *(const short8*)(zq + (mt * 16 + lcol) * 40 + quad * 8);
        aL[mt] = *(const short8*)(zq + 1280 + (mt * 16 + lcol) * 40 + quad * 8);
    }
    #pragma unroll
    for (int j = 0; j < 8; ++j) {
        int code = (wave * 8 + j) * 16 + lcol;
        short8 bH = *(const short8*)(cbHT + (size_t)code * 512 + dcPrev + quad * 8);
        #pragma unroll
        for (int mt = 0; mt < 2; ++mt) {
            acc[mt][j] = __builtin_amdgcn_mfma_f32_16x16x32_bf16(aH[mt], bH, acc[mt][j], 0, 0, 0);
            acc[mt][j] = __builtin_amdgcn_mfma_f32_16x16x32_bf16(aL[mt], bH, acc[mt][j], 0, 0, 0);
        }
    }
    if (!flag) {   // fp32 inputs: third term zh*cbL
        #pragma unroll
        for (int j = 0; j < 8; ++j) {
            int code = (wave * 8 + j) * 16 + lcol;
            short8 bL = *(const short8*)(cbLT + (size_t)code * 512 + dcPrev + quad * 8);
            #pragma unroll
            for (int mt = 0; mt < 2; ++mt)
                acc[mt][j] = __builtin_amdgcn_mfma_f32_16x16x32_bf16(aH[mt], bL, acc[mt][j], 0, 0, 0);
        }
    }
}

// Coalesced out_z: lane group 0..31 = 32 consecutive positions of one d-row
// -> each scalar store instruction writes a full, aligned 128 B line.
static __device__ __forceinline__ void outz_step(
        const unsigned short* __restrict__ zq, int dcPrev, int t,
        int b, int SP0, float* __restrict__ out_z) {
    const int col = t & 31;        // position
    const int g = t >> 5;          // 8 groups x 4 d-rows
    ushort4 h = *(const ushort4*)(zq + col * 40 + g * 4);
    ushort4 l = *(const ushort4*)(zq + 1280 + col * 40 + g * 4);
    size_t base = (size_t)(b * 512 + dcPrev + g * 4) * 1024 + SP0 + col;
    out_z[base         ] = bfu(h.x) + bfu(l.x);
    out_z[base + 1024  ] = bfu(h.y) + bfu(l.y);
    out_z[base + 2048  ] = bfu(h.z) + bfu(l.z);
    out_z[base + 3072  ] = bfu(h.w) + bfu(l.w);
}

static __device__ __forceinline__ void bmerge(float& a1, int& ak, float& a2,
                                              float o1, int ok, float o2) {
    if (o1 < a1)      { a2 = fminf(a1, o2); a1 = o1; ak = ok; }
    else if (o1 > a1) { a2 = fminf(a2, o1); }
    else              { a2 = a1; if (ok < ak) ak = ok; }   // exact tie -> gap 0 (suspect)
}

// ---------------------------------------------------------------------------
// FUSED main v5: 1024 blocks x 32 pos (4 blocks/CU), single barrier per chunk.
//   iter dc: sync; conv(dc)->buf p; mfma(dc-32)<-buf 1-p; outz(dc-32)<-buf 1-p.
// LDS: patch 6144 B | z pairs 2x5120 B = 16384 B.
// ---------------------------------------------------------------------------
__global__ __launch_bounds__(256, 4) void k_main(
        const void* __restrict__ x, const float* __restrict__ cWe,
        const float* __restrict__ cbe, const int* __restrict__ nbadp,
        const unsigned short* __restrict__ cbHT, const unsigned short* __restrict__ cbLT,
        const float* __restrict__ cbT, const float* __restrict__ w2,
        float* __restrict__ out_z, float* __restrict__ out_e,
        int* __restrict__ idx, int* __restrict__ scnt, int* __restrict__ spos,
        int skipTail) {
    __shared__ __align__(16) char smc[16384];
    float* patch = (float*)smc;                               // [32][48] fp32
    unsigned short* zb = (unsigned short*)(smc + 6144);       // 2 pairs x 2560 shorts

    const int t = threadIdx.x;
    const int P0 = blockIdx.x * 32;
    const int b = P0 >> 10, SP0 = P0 & 1023;
    const int flag = (*nbadp == 0);
    const int wave = t >> 6, lane = t & 63;
    const int quad = lane >> 4, lcol = lane & 15;

    // stage x patches once: 32 pos x 48 taps
    for (int e = t; e < 1536; e += 256) {
        int pid = e / 48, kk = e % 48;
        int c = kk >> 4, r = (kk >> 2) & 3, s = kk & 3;
        int pos = P0 + pid;
        int bb = pos >> 10, sp = pos & 1023, i = sp >> 5, j = sp & 31;
        patch[pid * 48 + kk] = ldin(x, ((bb * 3 + c) * 128 + (i * 4 + r)) * 128 + (j * 4 + s), flag);
    }

    floatx4 acc[2][8];
    #pragma unroll
    for (int mt = 0; mt < 2; ++mt)
        #pragma unroll
        for (int j = 0; j < 8; ++j) acc[mt][j] = (floatx4){0.f, 0.f, 0.f, 0.f};

    __syncthreads();
    conv_step(patch, cWe, cbe, 0, t, zb);              // chunk 0 -> pair 0
    for (int dc = 32; dc < 512; dc += 32) {
        __syncthreads();
        const int p = (dc >> 5) & 1;
        conv_step(patch, cWe, cbe, dc, t, zb + p * 2560);
        mfma_step(zb + (p ^ 1) * 2560, cbHT, cbLT, dc - 32, wave, quad, lcol, flag, acc);
        outz_step(zb + (p ^ 1) * 2560, dc - 32, t, b, SP0, out_z);
    }
    __syncthreads();
    mfma_step(zb + 2560, cbHT, cbLT, 480, wave, quad, lcol, flag, acc);
    outz_step(zb + 2560, 480, t, b, SP0, out_z);

    // ---- epilogue: per-lane best/second, shuffle-reduce over 16 lanes ----
    float s1[2][4], s2[2][4]; int k1[2][4];
    #pragma unroll
    for (int mt = 0; mt < 2; ++mt)
        #pragma unroll
        for (int r = 0; r < 4; ++r) { s1[mt][r] = 1e30f; s2[mt][r] = 1e30f; k1[mt][r] = 511; }
    #pragma unroll
    for (int j = 0; j < 8; ++j) {
        int code = (wave * 8 + j) * 16 + lcol;
        float wk = w2[code];
        #pragma unroll
        for (int mt = 0; mt < 2; ++mt)
            #pragma unroll
            for (int r = 0; r < 4; ++r) {
                float s = wk - 2.f * acc[mt][j][r];
                bmerge(s1[mt][r], k1[mt][r], s2[mt][r], s, code, 1e30f);
            }
    }
    // overlay reduction arrays on patch region (dead after last conv + barrier)
    float* sS1 = (float*)smc;             // [32 pos][4 wave]
    int*   sK1 = (int*)(smc + 512);
    float* sS2 = (float*)(smc + 1024);
    int*   ii  = (int*)(smc + 1536);      // [32]
    #pragma unroll
    for (int mt = 0; mt < 2; ++mt)
        #pragma unroll
        for (int r = 0; r < 4; ++r) {
            float a1 = s1[mt][r], a2 = s2[mt][r]; int ak = k1[mt][r];
            #pragma unroll
            for (int m = 1; m < 16; m <<= 1) {
                float o1 = __shfl_xor(a1, m);
                float o2 = __shfl_xor(a2, m);
                int   ok = __shfl_xor(ak, m);
                bmerge(a1, ak, a2, o1, ok, o2);
            }
            if (lcol == 0) {
                int pos = mt * 16 + quad * 4 + r;
                sS1[pos * 4 + wave] = a1;
                sK1[pos * 4 + wave] = ak;
                sS2[pos * 4 + wave] = a2;
            }
        }
    __syncthreads();
    if (t < 32) {
        float a1 = sS1[t * 4]; int ak = sK1[t * 4]; float a2 = sS2[t * 4];
        #pragma unroll
        for (int w = 1; w < 4; ++w)
            bmerge(a1, ak, a2, sS1[t * 4 + w], sK1[t * 4 + w], sS2[t * 4 + w]);
        ak &= 511;
        ii[t] = ak;
        idx[P0 + t] = ak;
        if (a2 - a1 < EPS_GAP) {
            int slot = atomicAdd(scnt, 1);
            if (slot < MAXSUS) spos[slot] = P0 + t;
        }
    }
    __syncthreads();

    // ---- fused emb: out_e[b][d][SP0+sp] = cbT[ii[sp]][d] ----
    const int sp = t & 31, dq = t >> 5;   // 8 strips of 64 d
    const float* row = cbT + (size_t)ii[sp] * 512;
    const size_t obase = ((size_t)b * 512) * 1024 + SP0 + sp;
    for (int d0 = dq * 64; d0 < dq * 64 + 64; d0 += 4) {
        if (skipTail && b == 31 && d0 >= 448) break;
        float4 v = *(const float4*)(row + d0);
        out_e[obase + (size_t)(d0    ) * 1024] = v.x;
        out_e[obase + (size_t)(d0 + 1) * 1024] = v.y;
        out_e[obase + (size_t)(d0 + 2) * 1024] = v.z;
        out_e[obase + (size_t)(d0 + 3) * 1024] = v.w;
    }
}

// ---------------------------------------------------------------------------
// Exact fp64 rescore of suspect positions; patches idx and emb column.
// ---------------------------------------------------------------------------
__global__ __launch_bounds__(256) void k_rescore(
        const float* __restrict__ out_z, const float* __restrict__ cbT,
        const double* __restrict__ w2d, int* __restrict__ idx,
        const int* __restrict__ scnt, const int* __restrict__ spos,
        float* __restrict__ out_e, int skipTail) {
    __shared__ float zsh[512];
    __shared__ float rs[256];
    __shared__ int rk[256];
    __shared__ int bc[2];
    const int t = threadIdx.x;
    int n = *scnt; if (n > MAXSUS) n = MAXSUS;
    for (int s = blockIdx.x; s < n; s += gridDim.x) {
        int p = spos[s] & 32767;
        int b = p >> 10, sp = p & 1023;
        __syncthreads();
        zsh[t]       = out_z[(size_t)(b * 512 + t) * 1024 + sp];
        zsh[t + 256] = out_z[(size_t)(b * 512 + t + 256) * 1024 + sp];
        __syncthreads();
        float bs = 1e30f; int bk = 511;
        for (int cc = 0; cc < 2; ++cc) {
            int k = t + cc * 256;
            double a = 0.0;
            const float* row = cbT + (size_t)k * 512;
            for (int d = 0; d < 512; ++d) a = fma((double)zsh[d], (double)row[d], a);
            float sc = (float)(w2d[k] - 2.0 * a);
            if (sc < bs || (sc == bs && k < bk)) { bs = sc; bk = k; }
        }
        rs[t] = bs; rk[t] = bk;
        __syncthreads();
        for (int str = 128; str > 0; str >>= 1) {
            if (t < str) {
                float so = rs[t + str]; int ko = rk[t + str];
                if (so < rs[t] || (so == rs[t] && ko < rk[t])) { rs[t] = so; rk[t] = ko; }
            }
            __syncthreads();
        }
        if (t == 0) {
            int kstar = rk[0] & 511;
            int old = idx[p] & 511;
            bc[0] = kstar; bc[1] = (kstar != old);
            idx[p] = kstar;
        }
        __syncthreads();
        if (bc[1]) {
            int kk = bc[0];
            for (int d = t; d < 512; d += 256) {
                if (skipTail && b == 31 && d >= 448) continue;
                out_e[(size_t)(b * 512 + d) * 1024 + sp] = cbT[(size_t)kk * 512 + d];
            }
        }
    }
}

// ---------------------------------------------------------------------------
__global__ __launch_bounds__(256) void k_recon(
        const float* __restrict__ U, const int* __restrict__ idx,
        float* __restrict__ out_r) {
    const int pos = blockIdx.x * 256 + threadIdx.x;
    const int id = idx[pos] & 511;
    const int b = pos >> 10, sp = pos & 1023, i = sp >> 5, j = sp & 31;
    const float* u = &U[(size_t)id * 48];
    #pragma unroll
    for (int c = 0; c < 3; ++c)
        #pragma unroll
        for (int uu = 0; uu < 4; ++uu) {
            float4 q = *(const float4*)(&u[c * 16 + uu * 4]);
            float4 o;
            o.x = 1.f / (1.f + __expf(-q.x));
            o.y = 1.f / (1.f + __expf(-q.y));
            o.z = 1.f / (1.f + __expf(-q.z));
            o.w = 1.f / (1.f + __expf(-q.w));
            *(float4*)(&out_r[((size_t)((b * 3 + c) * 128) + (i * 4 + uu)) * 128 + j * 4]) = o;
        }
}

// ---------------------------------------------------------------------------
__global__ __launch_bounds__(1024) void k_fixup(
        const void* __restrict__ cb, const int* __restrict__ nbadp,
        const int* __restrict__ idx, float* __restrict__ out_e) {
    __shared__ int ii[1024];
    __shared__ int sflag;
    const int t = threadIdx.x;
    if (t == 0) sflag = (*nbadp == 0);
    ii[t] = idx[31744 + t] & 511;
    __syncthreads();
    const int flag = sflag;
    for (int e = t; e < 65536; e += 1024) {
        int d = 448 + (e >> 10), sp = e & 1023;
        out_e[((size_t)(31 * 512 + d)) * 1024 + sp] = ldin(cb, (size_t)d * 512 + ii[sp], flag);
    }
}

// ---------------------------------------------------------------------------
extern "C" void kernel_launch(void* const* d_in, const int* in_sizes, int n_in,
                              void* d_out, int out_size, void* d_ws, size_t ws_size,
                              hipStream_t stream) {
    const void* x  = d_in[0];
    const void* We = d_in[1];
    const void* be = d_in[2];
    const void* Wd = d_in[3];
    const void* bd = d_in[4];
    const void* cb = d_in[5];

    float* out   = (float*)d_out;
    float* out_r = out;                       // 1,572,864 fp32 (6.29 MB)
    float* out_z = out + 1572864;             // 16,777,216 fp32
    float* out_e = out + 18350080;            // 16,777,216 fp32

    // Read-mostly tables in out_r (recon overwrites at the very end):
    char* Rb = (char*)out_r;
    float* cbF          = (float*)(Rb);                    // 1,048,576 B
    float* cbT          = (float*)(Rb + 1048576);          // 1,048,576 B
    float* cWe          = (float*)(Rb + 2097152);          //    98,304 B
    float* cbe          = (float*)(Rb + 2195456);          //     2,048 B
    float* cWd          = (float*)(Rb + 2197504);          //    98,304 B
    float* cbd          = (float*)(Rb + 2295808);          //        64 B
    unsigned short* cbHT= (unsigned short*)(Rb + 2295872); //   524,288 B
    unsigned short* cbLT= (unsigned short*)(Rb + 2820160); //   524,288 B

    // Tail scratch: prefer d_ws; else last 256 KB of out_e (fixup required).
    int tailWS = (ws_size >= 262144) ? 1 : 0;
    char* Tbase = tailWS ? (char*)d_ws : ((char*)out_e + 66846720);
    int skipTail = tailWS ? 0 : 1;
    int*    idx  = (int*)   (Tbase);            // 131,072 B
    float*  U    = (float*) (Tbase + 131072);   //  98,304 B
    float*  w2   = (float*) (Tbase + 229376);   //   2,048 B
    double* w2d  = (double*)(Tbase + 231424);   //   4,096 B
    int*    nbad = (int*)   (Tbase + 235520);   //      64 B
    int*    scnt = (int*)   (Tbase + 235584);   //      64 B
    int*    spos = (int*)   (Tbase + 235648);   //  16,384 B

    k_init<<<1, 1, 0, stream>>>(scnt, nbad);
    k_sniff<<<64, 64, 0, stream>>>(cb, nbad);
    k_canonW<<<195, 256, 0, stream>>>(We, be, Wd, bd, nbad, cWe, cbe, cWd, cbd);
    k_prepcb<<<dim3(8, 8), 256, 0, stream>>>(cb, nbad, cbF, cbT, cbHT, cbLT);
    k_w2<<<512, 64, 0, stream>>>(cbT, w2, w2d);
    k_udec<<<128, 256, 0, stream>>>(cbF, cWd, cbd, U);

    k_main<<<1024, 256, 0, stream>>>(x, cWe, cbe, nbad, cbHT, cbLT, cbT, w2,
                                     out_z, out_e, idx, scnt, spos, skipTail);

    k_rescore<<<128, 256, 0, stream>>>(out_z, cbT, w2d, idx, scnt, spos, out_e, skipTail);
    k_recon<<<128, 256, 0, stream>>>(U, idx, out_r);
    if (skipTail)
        k_fixup<<<1, 1024, 0, stream>>>(cb, nbad, idx, out_e);
}